// Round 2
// baseline (2148.526 us; speedup 1.0000x reference)
//
#include <hip/hip_runtime.h>
#include <hip/hip_bf16.h>

#define E_N   10000
#define SB_N  49
#define SBR_N 19
#define C_N   128
#define H_N   256
#define NBF_N 512
#define KPROJ 4864   // 2*SBR*C
#define NOUT  2432   // SBR*C

__device__ __forceinline__ float silu_f(float v) { return v / (1.0f + __expf(-v)); }

// ---------------------------------------------------------------------------
// Generic fp32 GEMM: C[M,N] = silu(A[M,K] @ B[K,N] + bias[N]) [* gate].
// BM=BN=64, BK=16. 256 threads, 4x4 micro-tile per thread, fp32 accumulate.
// GATED=1: multiply by gate[(i0+m)/2, n] after silu (proj GEMM).
// Requires: K % 16 == 0, N % 64 == 0. M may be ragged.
// ---------------------------------------------------------------------------
template<int GATED>
__launch_bounds__(256)
__global__ void gemm_silu(const float* __restrict__ A, const float* __restrict__ B,
                          const float* __restrict__ bias, const float* __restrict__ gate,
                          float* __restrict__ C, int M, int N, int K, int i0)
{
    __shared__ float As[16][64];   // [kk][m]
    __shared__ float Bs[16][64];   // [kk][n]
    const int tid = threadIdx.x;
    const int tm = tid & 15;
    const int tn = tid >> 4;
    const int m0 = blockIdx.x * 64;
    const int n0 = blockIdx.y * 64;

    const int ar = tid >> 2;         // 0..63 : A row in tile
    const int ak = (tid & 3) << 2;   // 0,4,8,12 : A k quad
    const int bk = tid >> 4;         // 0..15 : B k row
    const int bn = (tid & 15) << 2;  // 0..60 : B n quad

    float acc[4][4] = {{0.f,0.f,0.f,0.f},{0.f,0.f,0.f,0.f},
                       {0.f,0.f,0.f,0.f},{0.f,0.f,0.f,0.f}};

    for (int k0 = 0; k0 < K; k0 += 16) {
        float4 av = make_float4(0.f, 0.f, 0.f, 0.f);
        const int gm = m0 + ar;
        if (gm < M) av = *(const float4*)(A + (size_t)gm * K + (k0 + ak));
        const float4 bv = *(const float4*)(B + (size_t)(k0 + bk) * N + (n0 + bn));
        __syncthreads();   // previous iteration's readers done
        As[ak + 0][ar] = av.x; As[ak + 1][ar] = av.y;
        As[ak + 2][ar] = av.z; As[ak + 3][ar] = av.w;
        *(float4*)&Bs[bk][bn] = bv;
        __syncthreads();
        #pragma unroll
        for (int kk = 0; kk < 16; ++kk) {
            const float4 a = *(const float4*)&As[kk][tm << 2];
            const float4 b = *(const float4*)&Bs[kk][tn << 2];
            acc[0][0] += a.x * b.x; acc[0][1] += a.x * b.y; acc[0][2] += a.x * b.z; acc[0][3] += a.x * b.w;
            acc[1][0] += a.y * b.x; acc[1][1] += a.y * b.y; acc[1][2] += a.y * b.z; acc[1][3] += a.y * b.w;
            acc[2][0] += a.z * b.x; acc[2][1] += a.z * b.y; acc[2][2] += a.z * b.z; acc[2][3] += a.z * b.w;
            acc[3][0] += a.w * b.x; acc[3][1] += a.w * b.y; acc[3][2] += a.w * b.z; acc[3][3] += a.w * b.w;
        }
    }

    #pragma unroll
    for (int i = 0; i < 4; ++i) {
        const int gm = m0 + (tm << 2) + i;
        if (gm >= M) continue;
        #pragma unroll
        for (int j = 0; j < 4; ++j) {
            const int gn = n0 + (tn << 2) + j;
            float v = acc[i][j] + bias[gn];
            v = silu_f(v);
            if (GATED) v *= gate[(size_t)((i0 + gm) >> 1) * H_N + gn];
            C[(size_t)gm * N + gn] = v;
        }
    }
}

// ---------------------------------------------------------------------------
// Rotate: rot[ii, part*2432 + s*128 + c] = sum_b wigner[i0+ii, s, b] * x[node, b, c]
// node = edge_index[part][ (i0+ii)/2 ].  One block per row ii, 256 threads.
// ---------------------------------------------------------------------------
__launch_bounds__(256)
__global__ void rotate_kernel(const float* __restrict__ x, const float* __restrict__ wigner,
                              const int* __restrict__ eidx, float* __restrict__ rot, int i0)
{
    __shared__ float wig[SBR_N * SB_N];     // 931 floats
    __shared__ float xs[SB_N * C_N];        // 6272 floats (one part at a time)
    const int ii = blockIdx.x;
    const int i = i0 + ii;
    const int e = i >> 1;
    const int tid = threadIdx.x;
    const int c = tid & 127;
    const int sg = tid >> 7;               // 0/1 : s-group

    for (int t = tid; t < SBR_N * SB_N; t += 256)
        wig[t] = wigner[(size_t)i * (SBR_N * SB_N) + t];

    for (int part = 0; part < 2; ++part) {
        const int node = eidx[part * E_N + e];
        __syncthreads();  // previous part's compute done (also covers wig load)
        for (int t = tid; t < (SB_N * C_N) / 4; t += 256)
            *(float4*)&xs[t * 4] = *(const float4*)(x + (size_t)node * (SB_N * C_N) + t * 4);
        __syncthreads();
        for (int s = sg; s < SBR_N; s += 2) {
            float acc = 0.f;
            #pragma unroll 7
            for (int b = 0; b < SB_N; ++b)
                acc += wig[s * SB_N + b] * xs[b * C_N + c];
            rot[(size_t)ii * KPROJ + part * NOUT + s * C_N + c] = acc;
        }
    }
}

// ---------------------------------------------------------------------------
// Combine: mean over Y=2 rotations + inverse Wigner:
// out[e, b, c] = sum_s wigner_inv[e, b, s] * 0.5*(h3[2eb, s*128+c] + h3[2eb+1, s*128+c])
// One block per edge (128 threads = c).
// ---------------------------------------------------------------------------
__launch_bounds__(128)
__global__ void combine_kernel(const float* __restrict__ h3, const float* __restrict__ wigner_inv,
                               float* __restrict__ out, int e0)
{
    __shared__ float ms[SBR_N * C_N];       // 2432 floats
    __shared__ float wv[SB_N * SBR_N];      // 931 floats
    const int eb = blockIdx.x;
    const int e = e0 + eb;
    const int c = threadIdx.x;              // 0..127

    #pragma unroll
    for (int s = 0; s < SBR_N; ++s) {
        const float a = h3[(size_t)(2 * eb) * NOUT + s * C_N + c];
        const float b = h3[(size_t)(2 * eb + 1) * NOUT + s * C_N + c];
        ms[s * C_N + c] = 0.5f * (a + b);
    }
    for (int t = c; t < SB_N * SBR_N; t += 128)
        wv[t] = wigner_inv[(size_t)e * (SB_N * SBR_N) + t];
    __syncthreads();

    for (int b = 0; b < SB_N; ++b) {
        float acc = 0.f;
        #pragma unroll
        for (int s = 0; s < SBR_N; ++s)
            acc += wv[b * SBR_N + s] * ms[s * C_N + c];
        out[(size_t)e * (SB_N * C_N) + b * C_N + c] = acc;
    }
}

// ---------------------------------------------------------------------------
extern "C" void kernel_launch(void* const* d_in, const int* in_sizes, int n_in,
                              void* d_out, int out_size, void* d_ws, size_t ws_size,
                              hipStream_t stream)
{
    const float* x          = (const float*)d_in[0];
    const float* x_edge     = (const float*)d_in[1];
    const int*   eidx       = (const int*)d_in[2];
    const float* wigner     = (const float*)d_in[3];
    const float* wigner_inv = (const float*)d_in[4];
    const float* w_dist     = (const float*)d_in[5];
    const float* b_dist     = (const float*)d_in[6];
    const float* w_proj     = (const float*)d_in[7];
    const float* b_proj     = (const float*)d_in[8];
    const float* w_edge     = (const float*)d_in[9];
    const float* b_edge     = (const float*)d_in[10];
    const float* w_out      = (const float*)d_in[11];
    const float* b_out      = (const float*)d_in[12];
    float* out = (float*)d_out;

    char* ws = (char*)d_ws;
    const size_t gate_bytes = (size_t)E_N * H_N * sizeof(float);
    const size_t off = (gate_bytes + 255) & ~(size_t)255;
    // per EY-row: rot (4864) + h1 (256) + h2 (256), all fp32
    const size_t per_row = (size_t)(KPROJ + H_N + H_N) * sizeof(float);   // 21504 B
    const size_t avail = ws_size > off ? ws_size - off : 0;
    long cimax = (long)(avail / per_row);
    if (cimax > 2L * E_N) cimax = 2L * E_N;
    cimax &= ~1L;             // even (Y=2 pairs must not split)
    if (cimax < 2) cimax = 2; // last-resort (assumes ws is adequate)

    float* gate = (float*)ws;
    float* rot  = (float*)(ws + off);            // [cimax, 4864]; reused as h3 [cimax, 2432]
    float* h1   = rot + (size_t)cimax * KPROJ;   // [cimax, 256]
    float* h2   = h1 + (size_t)cimax * H_N;      // [cimax, 256]

    // 1. gate[e,h] = silu(x_edge @ w_dist + b_dist)
    gemm_silu<0><<<dim3((E_N + 63) / 64, H_N / 64), 256, 0, stream>>>(
        x_edge, w_dist, b_dist, nullptr, gate, E_N, H_N, NBF_N, 0);

    for (long i0 = 0; i0 < 2L * E_N; i0 += cimax) {
        long ci = 2L * E_N - i0;
        if (ci > cimax) ci = cimax;
        const unsigned gb = (unsigned)((ci + 63) / 64);

        // 2. rotate source+target into rot[ci, 4864]
        rotate_kernel<<<dim3((unsigned)ci), 256, 0, stream>>>(x, wigner, eidx, rot, (int)i0);

        // 3. h1 = silu(rot @ w_proj + b_proj) * gate[e]
        gemm_silu<1><<<dim3(gb, H_N / 64), 256, 0, stream>>>(
            rot, w_proj, b_proj, gate, h1, (int)ci, H_N, KPROJ, (int)i0);

        // 4. h2 = silu(h1 @ w_edge + b_edge)
        gemm_silu<0><<<dim3(gb, H_N / 64), 256, 0, stream>>>(
            h1, w_edge, b_edge, nullptr, h2, (int)ci, H_N, H_N, 0);

        // 5. h3 = silu(h2 @ w_out + b_out)   (reuses rot buffer)
        gemm_silu<0><<<dim3(gb, NOUT / 64), 256, 0, stream>>>(
            h2, w_out, b_out, nullptr, rot, (int)ci, NOUT, H_N, 0);

        // 6. out[e] = wigner_inv[e] @ mean_Y(h3)
        combine_kernel<<<dim3((unsigned)(ci / 2)), 128, 0, stream>>>(
            rot, wigner_inv, out, (int)(i0 / 2));
    }
}